// Round 1
// 15805.991 us; speedup vs baseline: 1.0817x; 1.0817x over previous
//
#include <hip/hip_runtime.h>
#include <hip/hip_bf16.h>

// GRU forward. B=128, S=1024, I=256, H=512.
// d_in: inputs f32 [128][1024][256], W_in f32 [256][1536], W_h f32 [512][1536],
//       bias f32 [3072] (b_in | b_h)
// d_out: hidden_sequence f32 [128][1024][512] then h_last f32 [128][512]
//
// Phase 1: x_proj = inputs@W_in + b_in, fp32 GEMM, stored bf16 in d_ws with a
//          per-scan-block sliced layout X[t][g][b][48].
// Phase 2: persistent 32-block scan. Block g owns h-cols [g*16, g*16+16):
//          W_h slice (48 cols) bf16 in LDS forever; per step MFMA
//          h[128][512]_bf16 @ Wh_slice -> [128][48], fp32 epilogue, global
//          h double-buffer (bf16) + per-step device-scope flag barrier.
//
// R1 changes (latency-chain surgery, numerics identical):
//  - all 32 A-operand loads hoisted to registers (1 IF roundtrip, not 4)
//  - X[t] prefetched (nontemporal) at top of step, hidden under MFMA
//  - out_seq stores deferred until AFTER the flag release (drain in spin),
//    nontemporal so the pre-flag fence/wbl2 only covers the 4KB h-slice
//  - W LDS tile re-laid out [gate][kstep][lane][8] -> lane-linear ds_read_b128
//  - h carry moved from LDS to registers
//
// d_ws layout: [hA 128K][hB 128K][flags 128B pad to 512][X 402,653,184 B]

#define B_DIM 128
#define S_DIM 1024
#define I_DIM 256
#define H_DIM 512
#define G_DIM 1536
#define NBLK 32
#define SLICE 16
#define SL3 48

typedef __bf16 bf16x8 __attribute__((ext_vector_type(8)));
typedef float floatx4 __attribute__((ext_vector_type(4)));

static __device__ __forceinline__ float bf2f(unsigned short u) {
    union { unsigned int i; float f; } v;
    v.i = ((unsigned int)u) << 16;
    return v.f;
}

static __device__ __forceinline__ unsigned short f2bf(float f) {
    union { float f; unsigned int i; } v;
    v.f = f;
    unsigned int lsb = (v.i >> 16) & 1;
    v.i += 0x7fffu + lsb;
    return (unsigned short)(v.i >> 16);
}

static __device__ __forceinline__ float sigmoidf_fast(float x) {
    return 1.0f / (1.0f + __expf(-x));   // x<<0: exp->inf -> 0 (graceful)
}
static __device__ __forceinline__ float tanhf_fast(float x) {
    // 1 - 2/(e^{2x}+1); overflow-safe: e^inf -> inf -> 2/inf=0 -> 1
    return 1.0f - 2.0f / (__expf(2.0f * x) + 1.0f);
}

// ---------------------------------------------------------------------------
// Phase 1: x_proj GEMM (M=131072, K=256, N=1536), fp32, bf16 sliced output.
// ---------------------------------------------------------------------------
#define BM 64
#define BN 64
#define BK 16

__global__ __launch_bounds__(256) void xproj_gemm(
    const float* __restrict__ A,      // [131072][256]
    const float* __restrict__ W,      // [256][1536]
    const float* __restrict__ bias,   // b_in at offset 0
    unsigned short* __restrict__ X)   // sliced layout [t][32][128][48]
{
    __shared__ float As[BK][BM + 1];
    __shared__ float Bs[BK][BN];

    const int tid = threadIdx.x;
    const int tx = tid & 15;
    const int ty = tid >> 4;
    const long m0 = (long)blockIdx.x * BM;
    const int n0 = blockIdx.y * BN;

    const int arow = tid >> 2;
    const int akc = (tid & 3) * 4;
    const int bkr = tid >> 4;
    const int bnc = (tid & 15) * 4;

    float acc[4][4] = {};

    for (int k0 = 0; k0 < I_DIM; k0 += BK) {
        float4 av = *(const float4*)(A + (m0 + arow) * I_DIM + k0 + akc);
        As[akc + 0][arow] = av.x;
        As[akc + 1][arow] = av.y;
        As[akc + 2][arow] = av.z;
        As[akc + 3][arow] = av.w;
        float4 bv = *(const float4*)(W + (long)(k0 + bkr) * G_DIM + n0 + bnc);
        *(float4*)&Bs[bkr][bnc] = bv;
        __syncthreads();
#pragma unroll
        for (int k = 0; k < BK; ++k) {
            float a0 = As[k][ty * 4 + 0];
            float a1 = As[k][ty * 4 + 1];
            float a2 = As[k][ty * 4 + 2];
            float a3 = As[k][ty * 4 + 3];
            float4 b = *(const float4*)&Bs[k][tx * 4];
            acc[0][0] += a0 * b.x; acc[0][1] += a0 * b.y; acc[0][2] += a0 * b.z; acc[0][3] += a0 * b.w;
            acc[1][0] += a1 * b.x; acc[1][1] += a1 * b.y; acc[1][2] += a1 * b.z; acc[1][3] += a1 * b.w;
            acc[2][0] += a2 * b.x; acc[2][1] += a2 * b.y; acc[2][2] += a2 * b.z; acc[2][3] += a2 * b.w;
            acc[3][0] += a3 * b.x; acc[3][1] += a3 * b.y; acc[3][2] += a3 * b.z; acc[3][3] += a3 * b.w;
        }
        __syncthreads();
    }

    const int n = n0 + tx * 4;        // global gate column of acc[.][0]
    const int q = n >> 9;             // gate 0/1/2
    const int hc = n & 511;           // h-column
    const int g = hc >> 4;            // scan block slice
    const int c = hc & 15;            // col within slice
    const float b0v = bias[n + 0];
    const float b1v = bias[n + 1];
    const float b2v = bias[n + 2];
    const float b3v = bias[n + 3];
#pragma unroll
    for (int i = 0; i < 4; ++i) {
        const long m = m0 + ty * 4 + i;
        const int b = (int)(m >> 10);
        const int t = (int)(m & 1023);
        ushort4 o;
        o.x = f2bf(acc[i][0] + b0v);
        o.y = f2bf(acc[i][1] + b1v);
        o.z = f2bf(acc[i][2] + b2v);
        o.w = f2bf(acc[i][3] + b3v);
        size_t addr = (((size_t)t * NBLK + g) * B_DIM + b) * SL3 + q * SLICE + c;
        *(ushort4*)(X + addr) = o;
    }
}

// ---------------------------------------------------------------------------
// Phase 2: persistent MFMA scan. 32 blocks x 256 threads (4 waves).
// ---------------------------------------------------------------------------
__global__ __launch_bounds__(256, 1) void gru_scan_mfma(
    const float* __restrict__ Wh,       // [512][1536]
    const float* __restrict__ bias,     // b_h at +1536
    const unsigned short* __restrict__ X, // [t][32][128][48] bf16
    unsigned short* __restrict__ hA,    // [128][512] bf16 (zeroed)
    unsigned short* __restrict__ hB,    // [128][512] bf16
    int* __restrict__ flags,            // [32] (zeroed)
    float* __restrict__ out_seq,        // [128][1024][512]
    float* __restrict__ out_last)       // [128][512]
{
    // W slice, lane-linear layout: W2[gate][k-step][lane=quad*16+col][8 bf16].
    // Lane (quad,c) reads its 16B B-fragment for k-step i at &W2[q][i][lane][0]
    // -> per-lane byte address = lane*16 within each [64][8] plane: the
    // conflict-free ds_read_b128 pattern (m134). 48 KiB total.
    __shared__ __align__(16) unsigned short W2[3][SLICE][64][8];

    const int tid  = threadIdx.x;
    const int g    = blockIdx.x;
    const int lane = tid & 63;
    const int wav  = tid >> 6;        // 0..3
    const int c    = lane & 15;       // N-col within slice / output col
    const int quad = lane >> 4;       // 0..3

    // ---- one-time: W_h slice -> LDS (bf16, lane-linear MFMA-B layout) ----
    for (int idx = tid; idx < 3 * SLICE * H_DIM; idx += 256) {
        int q   = idx >> 13;          // / 8192
        int rem = idx & 8191;
        int cc  = rem >> 9;           // / 512  -> col within slice
        int k   = rem & 511;
        float w = Wh[(size_t)k * G_DIM + q * H_DIM + g * SLICE + cc];
        // element (col cc, k) -> k-step k>>5, quad (k>>3)&3, sub-k k&7
        W2[q][k >> 5][((k >> 3) & 3) * 16 + cc][k & 7] = f2bf(w);
    }
    __syncthreads();

    const float bhr = bias[G_DIM + 0 * H_DIM + g * SLICE + c];
    const float bhz = bias[G_DIM + 1 * H_DIM + g * SLICE + c];
    const float bhn = bias[G_DIM + 2 * H_DIM + g * SLICE + c];

    const int mt0 = wav * 2;          // this wave's first M-tile (of 8)
    const int kc  = quad << 3;        // k-chunk offset within a K=32 step

    // fp32 h carry for this thread's 8 (row, c) outputs — registers, not LDS
    float hcar[8];
#pragma unroll
    for (int i = 0; i < 8; ++i) hcar[i] = 0.0f;

    for (int t = 0; t < S_DIM; ++t) {
        const unsigned short* __restrict__ h_read  = (t & 1) ? hB : hA;
        unsigned short* __restrict__       h_write = (t & 1) ? hA : hB;

        // ---- X[t] prefetch (independent of h): issue FIRST, consume in
        //      epilogue. Latency hides under the A-loads + MFMA chain. ----
        const unsigned short* __restrict__ xp =
            X + ((size_t)t * NBLK + g) * (B_DIM * SL3);
        unsigned short xc[8][3];
#pragma unroll
        for (int mi = 0; mi < 2; ++mi)
#pragma unroll
            for (int r = 0; r < 4; ++r) {
                const int row = (mt0 + mi) * 16 + quad * 4 + r;
#pragma unroll
                for (int q = 0; q < 3; ++q)
                    xc[mi * 4 + r][q] = __builtin_nontemporal_load(
                        xp + row * SL3 + q * SLICE + c);
            }

        // ---- A-operand: hoist ALL 32 16B loads (one IF roundtrip) ----
        const unsigned short* a0p = h_read + (size_t)(mt0 * 16 + c) * H_DIM + kc;
        const unsigned short* a1p = h_read + (size_t)((mt0 + 1) * 16 + c) * H_DIM + kc;
        bf16x8 A0[16], A1[16];
#pragma unroll
        for (int i = 0; i < 16; ++i) {
            A0[i] = *(const bf16x8*)(a0p + i * 32);
            A1[i] = *(const bf16x8*)(a1p + i * 32);
        }

        floatx4 aR0 = {0.f, 0.f, 0.f, 0.f}, aZ0 = aR0, aN0 = aR0;
        floatx4 aR1 = aR0, aZ1 = aR0, aN1 = aR0;

#pragma unroll
        for (int i = 0; i < 16; ++i) {
            bf16x8 bR = *(const bf16x8*)&W2[0][i][lane][0];
            bf16x8 bZ = *(const bf16x8*)&W2[1][i][lane][0];
            bf16x8 bN = *(const bf16x8*)&W2[2][i][lane][0];
            aR0 = __builtin_amdgcn_mfma_f32_16x16x32_bf16(A0[i], bR, aR0, 0, 0, 0);
            aZ0 = __builtin_amdgcn_mfma_f32_16x16x32_bf16(A0[i], bZ, aZ0, 0, 0, 0);
            aN0 = __builtin_amdgcn_mfma_f32_16x16x32_bf16(A0[i], bN, aN0, 0, 0, 0);
            aR1 = __builtin_amdgcn_mfma_f32_16x16x32_bf16(A1[i], bR, aR1, 0, 0, 0);
            aZ1 = __builtin_amdgcn_mfma_f32_16x16x32_bf16(A1[i], bZ, aZ1, 0, 0, 0);
            aN1 = __builtin_amdgcn_mfma_f32_16x16x32_bf16(A1[i], bN, aN1, 0, 0, 0);
        }

        // ---- epilogue: fp32 gate math; h_write now, out_seq deferred ----
        float onew[8];
#pragma unroll
        for (int mi = 0; mi < 2; ++mi) {
            const floatx4 aR = mi ? aR1 : aR0;
            const floatx4 aZ = mi ? aZ1 : aZ0;
            const floatx4 aN = mi ? aN1 : aN0;
#pragma unroll
            for (int r = 0; r < 4; ++r) {
                const int i8  = mi * 4 + r;
                const int row = (mt0 + mi) * 16 + quad * 4 + r;   // batch row
                const float xr = bf2f(xc[i8][0]);
                const float xz = bf2f(xc[i8][1]);
                const float xn = bf2f(xc[i8][2]);
                const float hp = hcar[i8];
                const float rr = sigmoidf_fast(xr + aR[r] + bhr);
                const float zz = sigmoidf_fast(xz + aZ[r] + bhz);
                const float nn = tanhf_fast(xn + rr * (aN[r] + bhn));
                const float hn = (1.0f - zz) * nn + zz * hp;
                hcar[i8] = hn;
                onew[i8] = hn;
                h_write[(size_t)row * H_DIM + g * SLICE + c] = f2bf(hn);
            }
        }

        // ---- release: only the 4KB h-slice needs draining before the flag
        //      (out_seq is not issued yet -> not in the fence/wbl2 set) ----
        __threadfence();
        __syncthreads();
        if (tid == 0)
            __hip_atomic_store(&flags[g], t + 1, __ATOMIC_RELEASE, __HIP_MEMORY_SCOPE_AGENT);

        // ---- deferred output stores: nontemporal (never dirty L2), drain
        //      in the background while we spin on remote flags ----
#pragma unroll
        for (int mi = 0; mi < 2; ++mi)
#pragma unroll
            for (int r = 0; r < 4; ++r) {
                const int i8  = mi * 4 + r;
                const int row = (mt0 + mi) * 16 + quad * 4 + r;
                __builtin_nontemporal_store(
                    onew[i8],
                    &out_seq[(size_t)row * (S_DIM * H_DIM) + (size_t)t * H_DIM + g * SLICE + c]);
                if (t == S_DIM - 1)
                    out_last[(size_t)row * H_DIM + g * SLICE + c] = onew[i8];
            }

        // ---- device-scope barrier (skip after last step) ----
        if (t != S_DIM - 1) {
            if (tid < 64) {
                int ok;
                do {
                    int v = (lane < NBLK)
                        ? __hip_atomic_load(&flags[lane], __ATOMIC_RELAXED, __HIP_MEMORY_SCOPE_AGENT)
                        : (t + 1);
                    ok = __all(v >= t + 1);
                } while (!ok);
            }
            __threadfence();
            __syncthreads();
        }
    }
}

extern "C" void kernel_launch(void* const* d_in, const int* in_sizes, int n_in,
                              void* d_out, int out_size, void* d_ws, size_t ws_size,
                              hipStream_t stream) {
    const float* inputs = (const float*)d_in[0];
    const float* W_in   = (const float*)d_in[1];
    const float* W_h    = (const float*)d_in[2];
    const float* bias   = (const float*)d_in[3];

    float* out_seq  = (float*)d_out;
    float* out_last = (float*)d_out + (size_t)B_DIM * S_DIM * H_DIM;

    char* ws = (char*)d_ws;
    unsigned short* hA    = (unsigned short*)ws;                 // 131072 B
    unsigned short* hB    = (unsigned short*)(ws + 131072);      // 131072 B
    int*            flags = (int*)(ws + 262144);                 // 128 B
    unsigned short* X     = (unsigned short*)(ws + 262656);      // 402,653,184 B

    hipMemsetAsync(hA, 0, 131072, stream);
    hipMemsetAsync(flags, 0, 128, stream);

    dim3 g1(B_DIM * S_DIM / BM, G_DIM / BN);
    xproj_gemm<<<g1, 256, 0, stream>>>(inputs, W_in, bias, X);

    gru_scan_mfma<<<NBLK, 256, 0, stream>>>(W_h, bias, X, hA, hB, flags,
                                            out_seq, out_last);
}

// Round 2
// 12413.005 us; speedup vs baseline: 1.3773x; 1.2733x over previous
//
#include <hip/hip_runtime.h>
#include <hip/hip_bf16.h>

// GRU forward. B=128, S=1024, I=256, H=512.
// d_in: inputs f32 [128][1024][256], W_in f32 [256][1536], W_h f32 [512][1536],
//       bias f32 [3072] (b_in | b_h)
// d_out: hidden_sequence f32 [128][1024][512] then h_last f32 [128][512]
//
// Phase 1: x_proj = inputs@W_in + b_in, fp32 GEMM, stored bf16 in d_ws with a
//          per-scan-block sliced layout X[t][g][b][48].
// Phase 2: persistent 32-block scan. Block g owns h-cols [g*16, g*16+16):
//          W_h slice (48 cols) bf16 in LDS forever; per step MFMA
//          h[128][512]_bf16 @ Wh_slice -> [128][48], fp32 epilogue, global
//          h double-buffer (bf16) + per-step device-scope flag barrier.
//
// R2 changes (barrier surgery — protocol identical, plumbing minimal):
//  - flags padded to 128 B/block (own IF cacheline) -> kills poll contention
//  - minimal fences: per-wave fence(RELEASE,agent)+relaxed flag store (1 wbl2,
//    no inv) on arrive; relaxed spin + single fence(ACQUIRE,agent) on exit;
//    s_sleep backoff in the poll
//  - X[t+1] prefetch (reg double-buffer) + out_seq nt stores moved INTO the
//    spin window
//  - sched_barrier(0) forces the full 32-load A hoist (one IF roundtrip)
//
// d_ws layout: [hA 128K][hB 128K][flags 4096B][X 402,653,184 B]

#define B_DIM 128
#define S_DIM 1024
#define I_DIM 256
#define H_DIM 512
#define G_DIM 1536
#define NBLK 32
#define SLICE 16
#define SL3 48

typedef __bf16 bf16x8 __attribute__((ext_vector_type(8)));
typedef float floatx4 __attribute__((ext_vector_type(4)));

static __device__ __forceinline__ float bf2f(unsigned short u) {
    union { unsigned int i; float f; } v;
    v.i = ((unsigned int)u) << 16;
    return v.f;
}

static __device__ __forceinline__ unsigned short f2bf(float f) {
    union { float f; unsigned int i; } v;
    v.f = f;
    unsigned int lsb = (v.i >> 16) & 1;
    v.i += 0x7fffu + lsb;
    return (unsigned short)(v.i >> 16);
}

static __device__ __forceinline__ float sigmoidf_fast(float x) {
    return 1.0f / (1.0f + __expf(-x));   // x<<0: exp->inf -> 0 (graceful)
}
static __device__ __forceinline__ float tanhf_fast(float x) {
    // 1 - 2/(e^{2x}+1); overflow-safe: e^inf -> inf -> 2/inf=0 -> 1
    return 1.0f - 2.0f / (__expf(2.0f * x) + 1.0f);
}

// ---------------------------------------------------------------------------
// Phase 1: x_proj GEMM (M=131072, K=256, N=1536), fp32, bf16 sliced output.
// ---------------------------------------------------------------------------
#define BM 64
#define BN 64
#define BK 16

__global__ __launch_bounds__(256) void xproj_gemm(
    const float* __restrict__ A,      // [131072][256]
    const float* __restrict__ W,      // [256][1536]
    const float* __restrict__ bias,   // b_in at offset 0
    unsigned short* __restrict__ X)   // sliced layout [t][32][128][48]
{
    __shared__ float As[BK][BM + 1];
    __shared__ float Bs[BK][BN];

    const int tid = threadIdx.x;
    const int tx = tid & 15;
    const int ty = tid >> 4;
    const long m0 = (long)blockIdx.x * BM;
    const int n0 = blockIdx.y * BN;

    const int arow = tid >> 2;
    const int akc = (tid & 3) * 4;
    const int bkr = tid >> 4;
    const int bnc = (tid & 15) * 4;

    float acc[4][4] = {};

    for (int k0 = 0; k0 < I_DIM; k0 += BK) {
        float4 av = *(const float4*)(A + (m0 + arow) * I_DIM + k0 + akc);
        As[akc + 0][arow] = av.x;
        As[akc + 1][arow] = av.y;
        As[akc + 2][arow] = av.z;
        As[akc + 3][arow] = av.w;
        float4 bv = *(const float4*)(W + (long)(k0 + bkr) * G_DIM + n0 + bnc);
        *(float4*)&Bs[bkr][bnc] = bv;
        __syncthreads();
#pragma unroll
        for (int k = 0; k < BK; ++k) {
            float a0 = As[k][ty * 4 + 0];
            float a1 = As[k][ty * 4 + 1];
            float a2 = As[k][ty * 4 + 2];
            float a3 = As[k][ty * 4 + 3];
            float4 b = *(const float4*)&Bs[k][tx * 4];
            acc[0][0] += a0 * b.x; acc[0][1] += a0 * b.y; acc[0][2] += a0 * b.z; acc[0][3] += a0 * b.w;
            acc[1][0] += a1 * b.x; acc[1][1] += a1 * b.y; acc[1][2] += a1 * b.z; acc[1][3] += a1 * b.w;
            acc[2][0] += a2 * b.x; acc[2][1] += a2 * b.y; acc[2][2] += a2 * b.z; acc[2][3] += a2 * b.w;
            acc[3][0] += a3 * b.x; acc[3][1] += a3 * b.y; acc[3][2] += a3 * b.z; acc[3][3] += a3 * b.w;
        }
        __syncthreads();
    }

    const int n = n0 + tx * 4;        // global gate column of acc[.][0]
    const int q = n >> 9;             // gate 0/1/2
    const int hc = n & 511;           // h-column
    const int g = hc >> 4;            // scan block slice
    const int c = hc & 15;            // col within slice
    const float b0v = bias[n + 0];
    const float b1v = bias[n + 1];
    const float b2v = bias[n + 2];
    const float b3v = bias[n + 3];
#pragma unroll
    for (int i = 0; i < 4; ++i) {
        const long m = m0 + ty * 4 + i;
        const int b = (int)(m >> 10);
        const int t = (int)(m & 1023);
        ushort4 o;
        o.x = f2bf(acc[i][0] + b0v);
        o.y = f2bf(acc[i][1] + b1v);
        o.z = f2bf(acc[i][2] + b2v);
        o.w = f2bf(acc[i][3] + b3v);
        size_t addr = (((size_t)t * NBLK + g) * B_DIM + b) * SL3 + q * SLICE + c;
        *(ushort4*)(X + addr) = o;
    }
}

// ---------------------------------------------------------------------------
// Phase 2: persistent MFMA scan. 32 blocks x 256 threads (4 waves).
// ---------------------------------------------------------------------------
__global__ __launch_bounds__(256, 1) void gru_scan_mfma(
    const float* __restrict__ Wh,       // [512][1536]
    const float* __restrict__ bias,     // b_h at +1536
    const unsigned short* __restrict__ X, // [t][32][128][48] bf16
    unsigned short* __restrict__ hA,    // [128][512] bf16 (zeroed)
    unsigned short* __restrict__ hB,    // [128][512] bf16
    int* __restrict__ flags,            // [32*32] padded: flag g at g*32 (zeroed)
    float* __restrict__ out_seq,        // [128][1024][512]
    float* __restrict__ out_last)       // [128][512]
{
    // W slice, lane-linear layout: W2[gate][k-step][lane=quad*16+col][8 bf16].
    // Per-lane ds_read_b128 address = lane*16 within each [64][8] plane ->
    // conflict-free (verified R1: SQ_LDS_BANK_CONFLICT 2.9e7 -> 7e4).
    __shared__ __align__(16) unsigned short W2[3][SLICE][64][8];

    const int tid  = threadIdx.x;
    const int g    = blockIdx.x;
    const int lane = tid & 63;
    const int wav  = tid >> 6;        // 0..3
    const int c    = lane & 15;       // N-col within slice / output col
    const int quad = lane >> 4;       // 0..3

    // ---- one-time: W_h slice -> LDS (bf16, lane-linear MFMA-B layout) ----
    for (int idx = tid; idx < 3 * SLICE * H_DIM; idx += 256) {
        int q   = idx >> 13;          // / 8192
        int rem = idx & 8191;
        int cc  = rem >> 9;           // / 512  -> col within slice
        int k   = rem & 511;
        float w = Wh[(size_t)k * G_DIM + q * H_DIM + g * SLICE + cc];
        W2[q][k >> 5][((k >> 3) & 3) * 16 + cc][k & 7] = f2bf(w);
    }
    __syncthreads();

    const float bhr = bias[G_DIM + 0 * H_DIM + g * SLICE + c];
    const float bhz = bias[G_DIM + 1 * H_DIM + g * SLICE + c];
    const float bhn = bias[G_DIM + 2 * H_DIM + g * SLICE + c];

    const int mt0 = wav * 2;          // this wave's first M-tile (of 8)
    const int kc  = quad << 3;        // k-chunk offset within a K=32 step

    // fp32 h carry for this thread's 8 (row, c) outputs — registers
    float hcar[8];
#pragma unroll
    for (int i = 0; i < 8; ++i) hcar[i] = 0.0f;

    // ---- X register double-buffer; prefetch t=0 ----
    unsigned short xc[8][3];
    {
        const unsigned short* __restrict__ xp = X + ((size_t)g) * (B_DIM * SL3);
#pragma unroll
        for (int mi = 0; mi < 2; ++mi)
#pragma unroll
            for (int r = 0; r < 4; ++r) {
                const int row = (mt0 + mi) * 16 + quad * 4 + r;
#pragma unroll
                for (int q = 0; q < 3; ++q)
                    xc[mi * 4 + r][q] = __builtin_nontemporal_load(
                        xp + row * SL3 + q * SLICE + c);
            }
    }

    for (int t = 0; t < S_DIM; ++t) {
        const unsigned short* __restrict__ h_read  = (t & 1) ? hB : hA;
        unsigned short* __restrict__       h_write = (t & 1) ? hA : hB;

        // ---- A-operand: ALL 32 16B loads issued before any MFMA (one IF
        //      roundtrip). sched_barrier(0) stops the scheduler re-sinking
        //      them into the MFMA loop (R1: it did, VGPR=120 proves it). ----
        const unsigned short* a0p = h_read + (size_t)(mt0 * 16 + c) * H_DIM + kc;
        const unsigned short* a1p = h_read + (size_t)((mt0 + 1) * 16 + c) * H_DIM + kc;
        bf16x8 A0[16], A1[16];
#pragma unroll
        for (int i = 0; i < 16; ++i) {
            A0[i] = *(const bf16x8*)(a0p + i * 32);
            A1[i] = *(const bf16x8*)(a1p + i * 32);
        }
        __builtin_amdgcn_sched_barrier(0);

        floatx4 aR0 = {0.f, 0.f, 0.f, 0.f}, aZ0 = aR0, aN0 = aR0;
        floatx4 aR1 = aR0, aZ1 = aR0, aN1 = aR0;

#pragma unroll
        for (int i = 0; i < 16; ++i) {
            bf16x8 bR = *(const bf16x8*)&W2[0][i][lane][0];
            bf16x8 bZ = *(const bf16x8*)&W2[1][i][lane][0];
            bf16x8 bN = *(const bf16x8*)&W2[2][i][lane][0];
            aR0 = __builtin_amdgcn_mfma_f32_16x16x32_bf16(A0[i], bR, aR0, 0, 0, 0);
            aZ0 = __builtin_amdgcn_mfma_f32_16x16x32_bf16(A0[i], bZ, aZ0, 0, 0, 0);
            aN0 = __builtin_amdgcn_mfma_f32_16x16x32_bf16(A0[i], bN, aN0, 0, 0, 0);
            aR1 = __builtin_amdgcn_mfma_f32_16x16x32_bf16(A1[i], bR, aR1, 0, 0, 0);
            aZ1 = __builtin_amdgcn_mfma_f32_16x16x32_bf16(A1[i], bZ, aZ1, 0, 0, 0);
            aN1 = __builtin_amdgcn_mfma_f32_16x16x32_bf16(A1[i], bN, aN1, 0, 0, 0);
        }

        // ---- epilogue: fp32 gate math; h_write stores now ----
        float onew[8];
#pragma unroll
        for (int mi = 0; mi < 2; ++mi) {
            const floatx4 aR = mi ? aR1 : aR0;
            const floatx4 aZ = mi ? aZ1 : aZ0;
            const floatx4 aN = mi ? aN1 : aN0;
#pragma unroll
            for (int r = 0; r < 4; ++r) {
                const int i8  = mi * 4 + r;
                const int row = (mt0 + mi) * 16 + quad * 4 + r;   // batch row
                const float xr = bf2f(xc[i8][0]);
                const float xz = bf2f(xc[i8][1]);
                const float xn = bf2f(xc[i8][2]);
                const float hp = hcar[i8];
                const float rr = sigmoidf_fast(xr + aR[r] + bhr);
                const float zz = sigmoidf_fast(xz + aZ[r] + bhz);
                const float nn = tanhf_fast(xn + rr * (aN[r] + bhn));
                const float hn = (1.0f - zz) * nn + zz * hp;
                hcar[i8] = hn;
                onew[i8] = hn;
                h_write[(size_t)row * H_DIM + g * SLICE + c] = f2bf(hn);
            }
        }

        // ---- arrive: per-wave release fence (vmcnt0+wbl2, NO inv), then
        //      block barrier, then relaxed flag store to this block's own
        //      128B-padded line. ----
        if (t != S_DIM - 1) {
            __builtin_amdgcn_fence(__ATOMIC_RELEASE, "agent");
            __syncthreads();
            if (tid == 0)
                __hip_atomic_store(&flags[g << 5], t + 1, __ATOMIC_RELAXED,
                                   __HIP_MEMORY_SCOPE_AGENT);
        }

        // ---- overlap window (runs while remote blocks finish): prefetch
        //      X[t+1], then drain out_seq (nontemporal, never dirties L2) ----
        unsigned short xcn[8][3];
        if (t != S_DIM - 1) {
            const unsigned short* __restrict__ xpn =
                X + ((size_t)(t + 1) * NBLK + g) * (B_DIM * SL3);
#pragma unroll
            for (int mi = 0; mi < 2; ++mi)
#pragma unroll
                for (int r = 0; r < 4; ++r) {
                    const int row = (mt0 + mi) * 16 + quad * 4 + r;
#pragma unroll
                    for (int q = 0; q < 3; ++q)
                        xcn[mi * 4 + r][q] = __builtin_nontemporal_load(
                            xpn + row * SL3 + q * SLICE + c);
                }
        }
#pragma unroll
        for (int mi = 0; mi < 2; ++mi)
#pragma unroll
            for (int r = 0; r < 4; ++r) {
                const int i8  = mi * 4 + r;
                const int row = (mt0 + mi) * 16 + quad * 4 + r;
                __builtin_nontemporal_store(
                    onew[i8],
                    &out_seq[(size_t)row * (S_DIM * H_DIM) + (size_t)t * H_DIM + g * SLICE + c]);
                if (t == S_DIM - 1)
                    out_last[(size_t)row * H_DIM + g * SLICE + c] = onew[i8];
            }

        // ---- wait: wave 0 spins on 32 padded lines (one lane each, sleep
        //      backoff), single acquire fence (inv) on exit. ----
        if (t != S_DIM - 1) {
            if (tid < 64) {
                int ok;
                do {
                    int v = (lane < NBLK)
                        ? __hip_atomic_load(&flags[lane << 5], __ATOMIC_RELAXED,
                                            __HIP_MEMORY_SCOPE_AGENT)
                        : (t + 1);
                    ok = __all(v >= t + 1);
                    if (!ok) __builtin_amdgcn_s_sleep(1);
                } while (!ok);
                __builtin_amdgcn_fence(__ATOMIC_ACQUIRE, "agent");
            }
            __syncthreads();
#pragma unroll
            for (int i = 0; i < 8; ++i)
#pragma unroll
                for (int q = 0; q < 3; ++q)
                    xc[i][q] = xcn[i][q];
        }
    }
}

extern "C" void kernel_launch(void* const* d_in, const int* in_sizes, int n_in,
                              void* d_out, int out_size, void* d_ws, size_t ws_size,
                              hipStream_t stream) {
    const float* inputs = (const float*)d_in[0];
    const float* W_in   = (const float*)d_in[1];
    const float* W_h    = (const float*)d_in[2];
    const float* bias   = (const float*)d_in[3];

    float* out_seq  = (float*)d_out;
    float* out_last = (float*)d_out + (size_t)B_DIM * S_DIM * H_DIM;

    char* ws = (char*)d_ws;
    unsigned short* hA    = (unsigned short*)ws;                 // 131072 B
    unsigned short* hB    = (unsigned short*)(ws + 131072);      // 131072 B
    int*            flags = (int*)(ws + 262144);                 // 4096 B (padded)
    unsigned short* X     = (unsigned short*)(ws + 266240);      // 402,653,184 B

    hipMemsetAsync(hA, 0, 131072, stream);
    hipMemsetAsync(flags, 0, 4096, stream);

    dim3 g1(B_DIM * S_DIM / BM, G_DIM / BN);
    xproj_gemm<<<g1, 256, 0, stream>>>(inputs, W_in, bias, X);

    gru_scan_mfma<<<NBLK, 256, 0, stream>>>(W_h, bias, X, hA, hB, flags,
                                            out_seq, out_last);
}

// Round 3
// 10000.875 us; speedup vs baseline: 1.7096x; 1.2412x over previous
//
#include <hip/hip_runtime.h>
#include <hip/hip_bf16.h>

// GRU forward. B=128, S=1024, I=256, H=512.
// d_in: inputs f32 [128][1024][256], W_in f32 [256][1536], W_h f32 [512][1536],
//       bias f32 [3072] (b_in | b_h)
// d_out: hidden_sequence f32 [128][1024][512] then h_last f32 [128][512]
//
// Phase 1: x_proj = inputs@W_in + b_in, fp32 GEMM, stored bf16 in d_ws with a
//          per-scan-block sliced layout X[t][g][b][48].
// Phase 2: persistent 32-block scan. Block g owns h-cols [g*16, g*16+16):
//          W_h slice (48 cols) bf16 in LDS forever; per step MFMA
//          h[128][512]_bf16 @ Wh_slice -> [128][48], fp32 epilogue, global
//          h double-buffer (bf16) + per-step device-scope flag barrier.
//
// R3 changes (take L2 out of the coherence path — no wbl2, no buffer_inv):
//  - h double-buffer stores: inline-asm global_store_short sc0 sc1
//    (write-through to IF; vmcnt-acked at the coherence point)
//  - release = per-wave s_waitcnt vmcnt(0) + __syncthreads + relaxed flag
//    store (no fence(RELEASE) -> no buffer_wbl2 L2 walk per step)
//  - h loads: inline-asm global_load_dwordx4 sc0 sc1 (read IF, bypass
//    stale L1/L2) -> no fence(ACQUIRE)/buffer_inv per step; asm also makes
//    the 32-load hoist structural (R1/R2: scheduler kept sinking it)
//  - everything else (padded flags, X reg double-buffer, deferred nt
//    out_seq stores in the spin window) carried from R2
//
// d_ws layout: [hA 128K][hB 128K][flags 4096B][X 402,653,184 B]

#define B_DIM 128
#define S_DIM 1024
#define I_DIM 256
#define H_DIM 512
#define G_DIM 1536
#define NBLK 32
#define SLICE 16
#define SL3 48

typedef __bf16 bf16x8 __attribute__((ext_vector_type(8)));
typedef float floatx4 __attribute__((ext_vector_type(4)));
typedef unsigned int uintx4 __attribute__((ext_vector_type(4)));

static __device__ __forceinline__ float bf2f(unsigned short u) {
    union { unsigned int i; float f; } v;
    v.i = ((unsigned int)u) << 16;
    return v.f;
}

static __device__ __forceinline__ unsigned short f2bf(float f) {
    union { float f; unsigned int i; } v;
    v.f = f;
    unsigned int lsb = (v.i >> 16) & 1;
    v.i += 0x7fffu + lsb;
    return (unsigned short)(v.i >> 16);
}

static __device__ __forceinline__ float sigmoidf_fast(float x) {
    return 1.0f / (1.0f + __expf(-x));   // x<<0: exp->inf -> 0 (graceful)
}
static __device__ __forceinline__ float tanhf_fast(float x) {
    // 1 - 2/(e^{2x}+1); overflow-safe: e^inf -> inf -> 2/inf=0 -> 1
    return 1.0f - 2.0f / (__expf(2.0f * x) + 1.0f);
}

// Device-coherent (IF-level) 16B load: bypasses L1 (sc0) and L2 (sc1).
static __device__ __forceinline__ bf16x8 ldg_b128_dc(const unsigned short* p) {
    uintx4 r;
    asm volatile("global_load_dwordx4 %0, %1, off sc0 sc1"
                 : "=v"(r) : "v"(p));
    union { uintx4 u; bf16x8 b; } cv;
    cv.u = r;
    return cv.b;
}

// Device-coherent 16-bit store: write-through to IF.
static __device__ __forceinline__ void stg_b16_dc(unsigned short* p, unsigned short v) {
    unsigned int vi = v;
    asm volatile("global_store_short %0, %1, off sc0 sc1"
                 :: "v"(p), "v"(vi) : "memory");
}

static __device__ __forceinline__ void wait_vm0(void) {
    asm volatile("s_waitcnt vmcnt(0)" ::: "memory");
}

// ---------------------------------------------------------------------------
// Phase 1: x_proj GEMM (M=131072, K=256, N=1536), fp32, bf16 sliced output.
// ---------------------------------------------------------------------------
#define BM 64
#define BN 64
#define BK 16

__global__ __launch_bounds__(256) void xproj_gemm(
    const float* __restrict__ A,      // [131072][256]
    const float* __restrict__ W,      // [256][1536]
    const float* __restrict__ bias,   // b_in at offset 0
    unsigned short* __restrict__ X)   // sliced layout [t][32][128][48]
{
    __shared__ float As[BK][BM + 1];
    __shared__ float Bs[BK][BN];

    const int tid = threadIdx.x;
    const int tx = tid & 15;
    const int ty = tid >> 4;
    const long m0 = (long)blockIdx.x * BM;
    const int n0 = blockIdx.y * BN;

    const int arow = tid >> 2;
    const int akc = (tid & 3) * 4;
    const int bkr = tid >> 4;
    const int bnc = (tid & 15) * 4;

    float acc[4][4] = {};

    for (int k0 = 0; k0 < I_DIM; k0 += BK) {
        float4 av = *(const float4*)(A + (m0 + arow) * I_DIM + k0 + akc);
        As[akc + 0][arow] = av.x;
        As[akc + 1][arow] = av.y;
        As[akc + 2][arow] = av.z;
        As[akc + 3][arow] = av.w;
        float4 bv = *(const float4*)(W + (long)(k0 + bkr) * G_DIM + n0 + bnc);
        *(float4*)&Bs[bkr][bnc] = bv;
        __syncthreads();
#pragma unroll
        for (int k = 0; k < BK; ++k) {
            float a0 = As[k][ty * 4 + 0];
            float a1 = As[k][ty * 4 + 1];
            float a2 = As[k][ty * 4 + 2];
            float a3 = As[k][ty * 4 + 3];
            float4 b = *(const float4*)&Bs[k][tx * 4];
            acc[0][0] += a0 * b.x; acc[0][1] += a0 * b.y; acc[0][2] += a0 * b.z; acc[0][3] += a0 * b.w;
            acc[1][0] += a1 * b.x; acc[1][1] += a1 * b.y; acc[1][2] += a1 * b.z; acc[1][3] += a1 * b.w;
            acc[2][0] += a2 * b.x; acc[2][1] += a2 * b.y; acc[2][2] += a2 * b.z; acc[2][3] += a2 * b.w;
            acc[3][0] += a3 * b.x; acc[3][1] += a3 * b.y; acc[3][2] += a3 * b.z; acc[3][3] += a3 * b.w;
        }
        __syncthreads();
    }

    const int n = n0 + tx * 4;        // global gate column of acc[.][0]
    const int q = n >> 9;             // gate 0/1/2
    const int hc = n & 511;           // h-column
    const int g = hc >> 4;            // scan block slice
    const int c = hc & 15;            // col within slice
    const float b0v = bias[n + 0];
    const float b1v = bias[n + 1];
    const float b2v = bias[n + 2];
    const float b3v = bias[n + 3];
#pragma unroll
    for (int i = 0; i < 4; ++i) {
        const long m = m0 + ty * 4 + i;
        const int b = (int)(m >> 10);
        const int t = (int)(m & 1023);
        ushort4 o;
        o.x = f2bf(acc[i][0] + b0v);
        o.y = f2bf(acc[i][1] + b1v);
        o.z = f2bf(acc[i][2] + b2v);
        o.w = f2bf(acc[i][3] + b3v);
        size_t addr = (((size_t)t * NBLK + g) * B_DIM + b) * SL3 + q * SLICE + c;
        *(ushort4*)(X + addr) = o;
    }
}

// ---------------------------------------------------------------------------
// Phase 2: persistent MFMA scan. 32 blocks x 256 threads (4 waves).
// ---------------------------------------------------------------------------
__global__ __launch_bounds__(256, 1) void gru_scan_mfma(
    const float* __restrict__ Wh,       // [512][1536]
    const float* __restrict__ bias,     // b_h at +1536
    const unsigned short* __restrict__ X, // [t][32][128][48] bf16
    unsigned short* __restrict__ hA,    // [128][512] bf16 (zeroed)
    unsigned short* __restrict__ hB,    // [128][512] bf16
    int* __restrict__ flags,            // [32*32] padded: flag g at g*32 (zeroed)
    float* __restrict__ out_seq,        // [128][1024][512]
    float* __restrict__ out_last)       // [128][512]
{
    // W slice, lane-linear layout: W2[gate][k-step][lane=quad*16+col][8 bf16].
    // Per-lane ds_read_b128 address = lane*16 within each [64][8] plane ->
    // conflict-free (verified R1: SQ_LDS_BANK_CONFLICT 2.9e7 -> 7e4).
    __shared__ __align__(16) unsigned short W2[3][SLICE][64][8];

    const int tid  = threadIdx.x;
    const int g    = blockIdx.x;
    const int lane = tid & 63;
    const int wav  = tid >> 6;        // 0..3
    const int c    = lane & 15;       // N-col within slice / output col
    const int quad = lane >> 4;       // 0..3

    // ---- one-time: W_h slice -> LDS (bf16, lane-linear MFMA-B layout) ----
    for (int idx = tid; idx < 3 * SLICE * H_DIM; idx += 256) {
        int q   = idx >> 13;          // / 8192
        int rem = idx & 8191;
        int cc  = rem >> 9;           // / 512  -> col within slice
        int k   = rem & 511;
        float w = Wh[(size_t)k * G_DIM + q * H_DIM + g * SLICE + cc];
        W2[q][k >> 5][((k >> 3) & 3) * 16 + cc][k & 7] = f2bf(w);
    }
    __syncthreads();

    const float bhr = bias[G_DIM + 0 * H_DIM + g * SLICE + c];
    const float bhz = bias[G_DIM + 1 * H_DIM + g * SLICE + c];
    const float bhn = bias[G_DIM + 2 * H_DIM + g * SLICE + c];

    const int mt0 = wav * 2;          // this wave's first M-tile (of 8)
    const int kc  = quad << 3;        // k-chunk offset within a K=32 step

    // fp32 h carry for this thread's 8 (row, c) outputs — registers
    float hcar[8];
#pragma unroll
    for (int i = 0; i < 8; ++i) hcar[i] = 0.0f;

    // ---- X register double-buffer; prefetch t=0 ----
    unsigned short xc[8][3];
    {
        const unsigned short* __restrict__ xp = X + ((size_t)g) * (B_DIM * SL3);
#pragma unroll
        for (int mi = 0; mi < 2; ++mi)
#pragma unroll
            for (int r = 0; r < 4; ++r) {
                const int row = (mt0 + mi) * 16 + quad * 4 + r;
#pragma unroll
                for (int q = 0; q < 3; ++q)
                    xc[mi * 4 + r][q] = __builtin_nontemporal_load(
                        xp + row * SL3 + q * SLICE + c);
            }
    }

    for (int t = 0; t < S_DIM; ++t) {
        const unsigned short* __restrict__ h_read  = (t & 1) ? hB : hA;
        unsigned short* __restrict__       h_write = (t & 1) ? hA : hB;

        // ---- A-operand: 32 device-coherent 16B loads (IF-served, bypass
        //      stale L1/L2), issued as one batch; single vmcnt(0) drain.
        //      asm loads cannot be re-sunk into the MFMA loop. ----
        const unsigned short* a0p = h_read + (size_t)(mt0 * 16 + c) * H_DIM + kc;
        const unsigned short* a1p = h_read + (size_t)((mt0 + 1) * 16 + c) * H_DIM + kc;
        bf16x8 A0[16], A1[16];
#pragma unroll
        for (int i = 0; i < 16; ++i) {
            A0[i] = ldg_b128_dc(a0p + i * 32);
            A1[i] = ldg_b128_dc(a1p + i * 32);
        }
        wait_vm0();
        __builtin_amdgcn_sched_barrier(0);

        floatx4 aR0 = {0.f, 0.f, 0.f, 0.f}, aZ0 = aR0, aN0 = aR0;
        floatx4 aR1 = aR0, aZ1 = aR0, aN1 = aR0;

#pragma unroll
        for (int i = 0; i < 16; ++i) {
            bf16x8 bR = *(const bf16x8*)&W2[0][i][lane][0];
            bf16x8 bZ = *(const bf16x8*)&W2[1][i][lane][0];
            bf16x8 bN = *(const bf16x8*)&W2[2][i][lane][0];
            aR0 = __builtin_amdgcn_mfma_f32_16x16x32_bf16(A0[i], bR, aR0, 0, 0, 0);
            aZ0 = __builtin_amdgcn_mfma_f32_16x16x32_bf16(A0[i], bZ, aZ0, 0, 0, 0);
            aN0 = __builtin_amdgcn_mfma_f32_16x16x32_bf16(A0[i], bN, aN0, 0, 0, 0);
            aR1 = __builtin_amdgcn_mfma_f32_16x16x32_bf16(A1[i], bR, aR1, 0, 0, 0);
            aZ1 = __builtin_amdgcn_mfma_f32_16x16x32_bf16(A1[i], bZ, aZ1, 0, 0, 0);
            aN1 = __builtin_amdgcn_mfma_f32_16x16x32_bf16(A1[i], bN, aN1, 0, 0, 0);
        }

        // ---- epilogue: fp32 gate math; h_write via write-through stores ----
        float onew[8];
#pragma unroll
        for (int mi = 0; mi < 2; ++mi) {
            const floatx4 aR = mi ? aR1 : aR0;
            const floatx4 aZ = mi ? aZ1 : aZ0;
            const floatx4 aN = mi ? aN1 : aN0;
#pragma unroll
            for (int r = 0; r < 4; ++r) {
                const int i8  = mi * 4 + r;
                const int row = (mt0 + mi) * 16 + quad * 4 + r;   // batch row
                const float xr = bf2f(xc[i8][0]);
                const float xz = bf2f(xc[i8][1]);
                const float xn = bf2f(xc[i8][2]);
                const float hp = hcar[i8];
                const float rr = sigmoidf_fast(xr + aR[r] + bhr);
                const float zz = sigmoidf_fast(xz + aZ[r] + bhz);
                const float nn = tanhf_fast(xn + rr * (aN[r] + bhn));
                const float hn = (1.0f - zz) * nn + zz * hp;
                hcar[i8] = hn;
                onew[i8] = hn;
                stg_b16_dc(h_write + (size_t)row * H_DIM + g * SLICE + c, f2bf(hn));
            }
        }

        // ---- arrive: h stores acked at IF (vmcnt0), all waves done
        //      (syncthreads), then relaxed flag store. No wbl2, no inv. ----
        if (t != S_DIM - 1) {
            wait_vm0();
            __syncthreads();
            if (tid == 0)
                __hip_atomic_store(&flags[g << 5], t + 1, __ATOMIC_RELAXED,
                                   __HIP_MEMORY_SCOPE_AGENT);
        }

        // ---- overlap window (runs while remote blocks finish): prefetch
        //      X[t+1], then drain out_seq (nontemporal, never dirties L2) ----
        unsigned short xcn[8][3];
        if (t != S_DIM - 1) {
            const unsigned short* __restrict__ xpn =
                X + ((size_t)(t + 1) * NBLK + g) * (B_DIM * SL3);
#pragma unroll
            for (int mi = 0; mi < 2; ++mi)
#pragma unroll
                for (int r = 0; r < 4; ++r) {
                    const int row = (mt0 + mi) * 16 + quad * 4 + r;
#pragma unroll
                    for (int q = 0; q < 3; ++q)
                        xcn[mi * 4 + r][q] = __builtin_nontemporal_load(
                            xpn + row * SL3 + q * SLICE + c);
                }
        }
#pragma unroll
        for (int mi = 0; mi < 2; ++mi)
#pragma unroll
            for (int r = 0; r < 4; ++r) {
                const int i8  = mi * 4 + r;
                const int row = (mt0 + mi) * 16 + quad * 4 + r;
                __builtin_nontemporal_store(
                    onew[i8],
                    &out_seq[(size_t)row * (S_DIM * H_DIM) + (size_t)t * H_DIM + g * SLICE + c]);
                if (t == S_DIM - 1)
                    out_last[(size_t)row * H_DIM + g * SLICE + c] = onew[i8];
            }

        // ---- wait: wave 0 spins on 32 padded lines (relaxed agent loads
        //      already bypass L1/L2 -> no acquire fence needed). ----
        if (t != S_DIM - 1) {
            if (tid < 64) {
                int ok;
                do {
                    int v = (lane < NBLK)
                        ? __hip_atomic_load(&flags[lane << 5], __ATOMIC_RELAXED,
                                            __HIP_MEMORY_SCOPE_AGENT)
                        : (t + 1);
                    ok = __all(v >= t + 1);
                    if (!ok) __builtin_amdgcn_s_sleep(1);
                } while (!ok);
            }
            __syncthreads();
#pragma unroll
            for (int i = 0; i < 8; ++i)
#pragma unroll
                for (int q = 0; q < 3; ++q)
                    xc[i][q] = xcn[i][q];
        }
    }
}

extern "C" void kernel_launch(void* const* d_in, const int* in_sizes, int n_in,
                              void* d_out, int out_size, void* d_ws, size_t ws_size,
                              hipStream_t stream) {
    const float* inputs = (const float*)d_in[0];
    const float* W_in   = (const float*)d_in[1];
    const float* W_h    = (const float*)d_in[2];
    const float* bias   = (const float*)d_in[3];

    float* out_seq  = (float*)d_out;
    float* out_last = (float*)d_out + (size_t)B_DIM * S_DIM * H_DIM;

    char* ws = (char*)d_ws;
    unsigned short* hA    = (unsigned short*)ws;                 // 131072 B
    unsigned short* hB    = (unsigned short*)(ws + 131072);      // 131072 B
    int*            flags = (int*)(ws + 262144);                 // 4096 B (padded)
    unsigned short* X     = (unsigned short*)(ws + 266240);      // 402,653,184 B

    hipMemsetAsync(hA, 0, 131072, stream);
    hipMemsetAsync(flags, 0, 4096, stream);

    dim3 g1(B_DIM * S_DIM / BM, G_DIM / BN);
    xproj_gemm<<<g1, 256, 0, stream>>>(inputs, W_in, bias, X);

    gru_scan_mfma<<<NBLK, 256, 0, stream>>>(W_h, bias, X, hA, hB, flags,
                                            out_seq, out_last);
}